// Round 4
// baseline (344.402 us; speedup 1.0000x reference)
//
#include <hip/hip_runtime.h>

typedef __bf16 bf16;
typedef __attribute__((ext_vector_type(8))) __bf16 bf16x8;
typedef __attribute__((ext_vector_type(4))) float f32x4;

#define MFMA_16x16x32(a, b, c) __builtin_amdgcn_mfma_f32_16x16x32_bf16((a), (b), (c), 0, 0, 0)

#define NEG_BIG (-1e30f)

__device__ __forceinline__ void gload_lds16(void* lds, const void* g) {
  __builtin_amdgcn_global_load_lds(
      (const __attribute__((address_space(1))) void*)g,
      (__attribute__((address_space(3))) void*)lds, 16, 0, 0);
}

// ---------------------------------------------------------------------------
// f32 -> bf16 conversion (vectorized: 8 el / thread). n8 = n/8.
// ---------------------------------------------------------------------------
__global__ void f32_to_bf16(const float* __restrict__ src, bf16* __restrict__ dst,
                            int n8) {
  const int i = blockIdx.x * blockDim.x + threadIdx.x;
  if (i >= n8) return;
  const float4 a = ((const float4*)src)[i * 2 + 0];
  const float4 b = ((const float4*)src)[i * 2 + 1];
  bf16x8 o;
  o[0] = (bf16)a.x; o[1] = (bf16)a.y; o[2] = (bf16)a.z; o[3] = (bf16)a.w;
  o[4] = (bf16)b.x; o[5] = (bf16)b.y; o[6] = (bf16)b.z; o[7] = (bf16)b.w;
  ((bf16x8*)dst)[i] = o;
}

// ---------------------------------------------------------------------------
// GEMM (BT): out = A[M,K] . W[N,K]^T + bias[N]   (m97 template)
// A, W bf16; bias f32 (direct from d_in).
// OUT_MODE 0: bf16, head layout ((b*16+h)*2048+t)*64+d          (Q, K)
// OUT_MODE 1: f32, plain row-major [M,N]                         (final proj)
// OUT_MODE 2: bf16, TRANSPOSED head layout ((b*16+h)*64+d)*2048+t  (V^T)
// ---------------------------------------------------------------------------
template <int OUT_MODE, typename OutT>
__global__ void gemm_bt(const bf16* __restrict__ A, const bf16* __restrict__ W,
                        const float* __restrict__ bias, OutT* __restrict__ out,
                        int M, int N, int K) {
  __shared__ __align__(16) bf16 As[128 * 32];
  __shared__ __align__(16) bf16 Bs[128 * 32];
  const int tid = threadIdx.x;
  const int wv = tid >> 6, lane = tid & 63;
  const int wr = wv >> 1, wc = wv & 1;
  const int lr = lane & 15, lg = lane >> 4;
  const int m0 = blockIdx.y * 128, n0 = blockIdx.x * 128;

  f32x4 acc[4][4] = {};

  for (int k0 = 0; k0 < K; k0 += 32) {
    __syncthreads();
#pragma unroll
    for (int j = 0; j < 2; ++j) {
      const int e8 = (j * 256 + tid) * 8;
      const int row = e8 >> 5, col = e8 & 31;
      gload_lds16(As + (size_t)(j * 256 + wv * 64) * 8,
                  A + (size_t)(m0 + row) * K + k0 + col);
      gload_lds16(Bs + (size_t)(j * 256 + wv * 64) * 8,
                  W + (size_t)(n0 + row) * K + k0 + col);
    }
    __syncthreads();
    bf16x8 af[4], bfr[4];
#pragma unroll
    for (int i = 0; i < 4; ++i)
      af[i] = *(const bf16x8*)&As[(wr * 64 + i * 16 + lr) * 32 + lg * 8];
#pragma unroll
    for (int j = 0; j < 4; ++j)
      bfr[j] = *(const bf16x8*)&Bs[(wc * 64 + j * 16 + lr) * 32 + lg * 8];
#pragma unroll
    for (int i = 0; i < 4; ++i)
#pragma unroll
      for (int j = 0; j < 4; ++j)
        acc[i][j] = MFMA_16x16x32(af[i], bfr[j], acc[i][j]);
  }

#pragma unroll
  for (int j = 0; j < 4; ++j) {
    const int n = n0 + wc * 64 + j * 16 + lr;
    const float bv = bias[n];
#pragma unroll
    for (int i = 0; i < 4; ++i) {
#pragma unroll
      for (int r = 0; r < 4; ++r) {
        const int m = m0 + wr * 64 + i * 16 + lg * 4 + r;
        const float v = acc[i][j][r] + bv;
        if (OUT_MODE == 0) {
          const int b = m >> 11, t = m & 2047, h = n >> 6, d = n & 63;
          out[((size_t)(b * 16 + h) * 2048 + t) * 64 + d] = (OutT)v;
        } else if (OUT_MODE == 2) {
          const int b = m >> 11, t = m & 2047, h = n >> 6, d = n & 63;
          out[((size_t)(b * 16 + h) * 64 + d) * 2048 + t] = (OutT)v;
        } else {
          out[(size_t)m * N + n] = (OutT)v;
        }
      }
    }
  }
}

// ---------------------------------------------------------------------------
// Causal flash attention — barrier-free kv-loop (round 4).
// Q,K in [B*H, T, D] bf16; Vt in [B*H, D, T] bf16 (pre-transposed by the V
// projection GEMM). Output att_out in [B,T,C] bf16.
// Block: 256 thr = 4 waves; 64 q-rows/block, wave w owns rows [q0+16w,+16).
// K and V^T fragments read DIRECTLY from global (L2-resident, 256KB/head).
// Only LDS use: per-wave P round-trip (wave-synchronous -> no barriers).
// ---------------------------------------------------------------------------
__global__ void attn_fwd(const bf16* __restrict__ Q, const bf16* __restrict__ Kk,
                         const bf16* __restrict__ Vt, bf16* __restrict__ attout) {
  __shared__ __align__(16) bf16 Ps[4][16][72];   // per-wave P [q][kv], padded

  const int tid = threadIdx.x;
  const int wv = tid >> 6, lane = tid & 63;
  const int lr = lane & 15, lg = lane >> 4;
  const int q0 = blockIdx.x * 64, bh = blockIdx.y;
  const size_t bhT = (size_t)bh * 2048;
  const bf16* Vh = Vt + (size_t)bh * 64 * 2048;  // [d][t]

  const int qrow = q0 + wv * 16 + lr;
  bf16x8 qf[2];
  qf[0] = *(const bf16x8*)(Q + (bhT + qrow) * 64 + lg * 8);
  qf[1] = *(const bf16x8*)(Q + (bhT + qrow) * 64 + 32 + lg * 8);

  f32x4 o[4] = {};
  float m_run[4] = {NEG_BIG, NEG_BIG, NEG_BIG, NEG_BIG};
  float l_run[4] = {0.f, 0.f, 0.f, 0.f};

  for (int kv0 = 0; kv0 <= q0; kv0 += 64) {
    // ---- S = Q . K^T, K fragments direct from global ----
    f32x4 s[4] = {};
#pragma unroll
    for (int j = 0; j < 4; ++j) {
      const int n = j * 16 + lr;  // kv row
      const bf16x8 kf0 = *(const bf16x8*)(Kk + (bhT + kv0 + n) * 64 + lg * 8);
      s[j] = MFMA_16x16x32(qf[0], kf0, s[j]);
      const bf16x8 kf1 = *(const bf16x8*)(Kk + (bhT + kv0 + n) * 64 + 32 + lg * 8);
      s[j] = MFMA_16x16x32(qf[1], kf1, s[j]);
    }
#pragma unroll
    for (int j = 0; j < 4; ++j) s[j] *= 0.125f;  // 1/sqrt(64)

    if (kv0 == q0) {  // diagonal tile: causal mask
#pragma unroll
      for (int j = 0; j < 4; ++j) {
        const int colk = kv0 + j * 16 + lr;
#pragma unroll
        for (int r = 0; r < 4; ++r) {
          const int rowq = q0 + wv * 16 + lg * 4 + r;
          if (colk > rowq) s[j][r] = NEG_BIG;
        }
      }
    }

    // ---- online softmax: 4 q-rows/lane (r); cols over 16 lanes x 4 j ----
#pragma unroll
    for (int r = 0; r < 4; ++r) {
      float mx = fmaxf(fmaxf(s[0][r], s[1][r]), fmaxf(s[2][r], s[3][r]));
      mx = fmaxf(mx, __shfl_xor(mx, 1));
      mx = fmaxf(mx, __shfl_xor(mx, 2));
      mx = fmaxf(mx, __shfl_xor(mx, 4));
      mx = fmaxf(mx, __shfl_xor(mx, 8));
      const float mnew = fmaxf(m_run[r], mx);
      const float fac = __expf(m_run[r] - mnew);  // 0 on first tile
      float rs = 0.f;
#pragma unroll
      for (int j = 0; j < 4; ++j) {
        const float p = __expf(s[j][r] - mnew);
        s[j][r] = p;
        rs += p;
      }
      rs += __shfl_xor(rs, 1);
      rs += __shfl_xor(rs, 2);
      rs += __shfl_xor(rs, 4);
      rs += __shfl_xor(rs, 8);
      l_run[r] = l_run[r] * fac + rs;
      m_run[r] = mnew;
#pragma unroll
      for (int jd = 0; jd < 4; ++jd) o[jd][r] *= fac;
    }

    // ---- P -> per-wave padded LDS (D-layout write, A-layout read) ----
#pragma unroll
    for (int j = 0; j < 4; ++j)
#pragma unroll
      for (int r = 0; r < 4; ++r)
        Ps[wv][lg * 4 + r][j * 16 + lr] = (bf16)s[j][r];
    const bf16x8 pf0 = *(const bf16x8*)&Ps[wv][lr][lg * 8];
    const bf16x8 pf1 = *(const bf16x8*)&Ps[wv][lr][32 + lg * 8];

    // ---- PV: o[q][d] += P[q][kv] * V[kv][d]; B-op direct from Vt[d][t] ----
#pragma unroll
    for (int jd = 0; jd < 4; ++jd) {
      const int n = jd * 16 + lr;  // d
      const bf16x8 vf0 = *(const bf16x8*)(Vh + (size_t)n * 2048 + kv0 + lg * 8);
      o[jd] = MFMA_16x16x32(pf0, vf0, o[jd]);
      const bf16x8 vf1 = *(const bf16x8*)(Vh + (size_t)n * 2048 + kv0 + 32 + lg * 8);
      o[jd] = MFMA_16x16x32(pf1, vf1, o[jd]);
    }
  }

  // ---- normalize + store att_out in [B,T,C] ----
  const int b = bh >> 4, h = bh & 15;
#pragma unroll
  for (int jd = 0; jd < 4; ++jd)
#pragma unroll
    for (int r = 0; r < 4; ++r) {
      const int rowq = q0 + wv * 16 + lg * 4 + r;
      const float ov = o[jd][r] / l_run[r];
      attout[((size_t)b * 2048 + rowq) * 1024 + h * 64 + jd * 16 + lr] = (bf16)ov;
    }
}

// ---------------------------------------------------------------------------
extern "C" void kernel_launch(void* const* d_in, const int* in_sizes, int n_in,
                              void* d_out, int out_size, void* d_ws, size_t ws_size,
                              hipStream_t stream) {
  // Inputs are FLOAT32 (reference dtype). Biases used directly as f32.
  const float* x   = (const float*)d_in[0];
  const float* xq  = (const float*)d_in[1];
  const float* Wq  = (const float*)d_in[2];
  const float* bq  = (const float*)d_in[3];
  const float* Wk  = (const float*)d_in[4];
  const float* bk  = (const float*)d_in[5];
  const float* Wv  = (const float*)d_in[6];
  const float* bv  = (const float*)d_in[7];
  const float* Wp  = (const float*)d_in[8];
  const float* bp  = (const float*)d_in[9];
  float* out = (float*)d_out;

  const size_t NTC = 4194304;  // B*T*C = 2*2048*1024
  const size_t NW  = 1048576;  // C*C
  bf16* ws = (bf16*)d_ws;
  bf16* XQb = ws;                    // [B*T, C]
  bf16* Xb  = XQb + NTC;             // [B*T, C]
  bf16* Wqb = Xb + NTC;
  bf16* Wkb = Wqb + NW;
  bf16* Wvb = Wkb + NW;
  bf16* Wpb = Wvb + NW;
  bf16* Qw  = Wpb + NW;              // [B*H, T, D]
  bf16* Kw  = Qw + NTC;
  bf16* Vtw = Kw + NTC;              // [B*H, D, T]  (pre-transposed)
  bf16* Aw  = Vtw + NTC;             // [B, T, C]

  dim3 blk(256);
  // f32 -> bf16 conversions
  f32_to_bf16<<<dim3((NTC / 8 + 255) / 256), blk, 0, stream>>>(xq, XQb, NTC / 8);
  f32_to_bf16<<<dim3((NTC / 8 + 255) / 256), blk, 0, stream>>>(x, Xb, NTC / 8);
  f32_to_bf16<<<dim3((NW / 8 + 255) / 256), blk, 0, stream>>>(Wq, Wqb, NW / 8);
  f32_to_bf16<<<dim3((NW / 8 + 255) / 256), blk, 0, stream>>>(Wk, Wkb, NW / 8);
  f32_to_bf16<<<dim3((NW / 8 + 255) / 256), blk, 0, stream>>>(Wv, Wvb, NW / 8);
  f32_to_bf16<<<dim3((NW / 8 + 255) / 256), blk, 0, stream>>>(Wp, Wpb, NW / 8);

  gemm_bt<0, bf16><<<dim3(8, 32), blk, 0, stream>>>(XQb, Wqb, bq, Qw, 4096, 1024, 1024);
  gemm_bt<0, bf16><<<dim3(8, 32), blk, 0, stream>>>(Xb,  Wkb, bk, Kw, 4096, 1024, 1024);
  gemm_bt<2, bf16><<<dim3(8, 32), blk, 0, stream>>>(Xb,  Wvb, bv, Vtw, 4096, 1024, 1024);
  attn_fwd<<<dim3(32, 32), blk, 0, stream>>>(Qw, Kw, Vtw, Aw);
  gemm_bt<1, float><<<dim3(8, 32), blk, 0, stream>>>(Aw, Wpb, bp, out, 4096, 1024, 1024);
}

// Round 5
// 227.474 us; speedup vs baseline: 1.5140x; 1.5140x over previous
//
#include <hip/hip_runtime.h>

typedef __bf16 bf16;
typedef __attribute__((ext_vector_type(8))) __bf16 bf16x8;
typedef __attribute__((ext_vector_type(4))) float f32x4;

#define MFMA_16x16x32(a, b, c) __builtin_amdgcn_mfma_f32_16x16x32_bf16((a), (b), (c), 0, 0, 0)

#define NEG_BIG (-1e30f)

__device__ __forceinline__ void gload_lds16(void* lds, const void* g) {
  __builtin_amdgcn_global_load_lds(
      (const __attribute__((address_space(1))) void*)g,
      (__attribute__((address_space(3))) void*)lds, 16, 0, 0);
}

// ---------------------------------------------------------------------------
// f32 -> bf16 conversion (vectorized: 8 el / thread). n8 = n/8.
// ---------------------------------------------------------------------------
__global__ void f32_to_bf16(const float* __restrict__ src, bf16* __restrict__ dst,
                            int n8) {
  const int i = blockIdx.x * blockDim.x + threadIdx.x;
  if (i >= n8) return;
  const float4 a = ((const float4*)src)[i * 2 + 0];
  const float4 b = ((const float4*)src)[i * 2 + 1];
  bf16x8 o;
  o[0] = (bf16)a.x; o[1] = (bf16)a.y; o[2] = (bf16)a.z; o[3] = (bf16)a.w;
  o[4] = (bf16)b.x; o[5] = (bf16)b.y; o[6] = (bf16)b.z; o[7] = (bf16)b.w;
  ((bf16x8*)dst)[i] = o;
}

// ---------------------------------------------------------------------------
// GEMM (BT): out = A[M,K] . W[N,K]^T + bias[N]   (m97 template)
// OUT_MODE 0: bf16, head layout ((b*16+h)*2048+t)*64+d            (Q, K)
// OUT_MODE 1: f32, plain row-major [M,N]                          (final proj)
// OUT_MODE 2: bf16, TRANSPOSED head layout ((b*16+h)*64+d)*2048+t (V^T)
// ---------------------------------------------------------------------------
template <int OUT_MODE, typename OutT>
__global__ void gemm_bt(const bf16* __restrict__ A, const bf16* __restrict__ W,
                        const float* __restrict__ bias, OutT* __restrict__ out,
                        int M, int N, int K) {
  __shared__ __align__(16) bf16 As[128 * 32];
  __shared__ __align__(16) bf16 Bs[128 * 32];
  const int tid = threadIdx.x;
  const int wv = tid >> 6, lane = tid & 63;
  const int wr = wv >> 1, wc = wv & 1;
  const int lr = lane & 15, lg = lane >> 4;
  const int m0 = blockIdx.y * 128, n0 = blockIdx.x * 128;

  f32x4 acc[4][4] = {};

  for (int k0 = 0; k0 < K; k0 += 32) {
    __syncthreads();
#pragma unroll
    for (int j = 0; j < 2; ++j) {
      const int e8 = (j * 256 + tid) * 8;
      const int row = e8 >> 5, col = e8 & 31;
      gload_lds16(As + (size_t)(j * 256 + wv * 64) * 8,
                  A + (size_t)(m0 + row) * K + k0 + col);
      gload_lds16(Bs + (size_t)(j * 256 + wv * 64) * 8,
                  W + (size_t)(n0 + row) * K + k0 + col);
    }
    __syncthreads();
    bf16x8 af[4], bfr[4];
#pragma unroll
    for (int i = 0; i < 4; ++i)
      af[i] = *(const bf16x8*)&As[(wr * 64 + i * 16 + lr) * 32 + lg * 8];
#pragma unroll
    for (int j = 0; j < 4; ++j)
      bfr[j] = *(const bf16x8*)&Bs[(wc * 64 + j * 16 + lr) * 32 + lg * 8];
#pragma unroll
    for (int i = 0; i < 4; ++i)
#pragma unroll
      for (int j = 0; j < 4; ++j)
        acc[i][j] = MFMA_16x16x32(af[i], bfr[j], acc[i][j]);
  }

#pragma unroll
  for (int j = 0; j < 4; ++j) {
    const int n = n0 + wc * 64 + j * 16 + lr;
    const float bv = bias[n];
#pragma unroll
    for (int i = 0; i < 4; ++i) {
#pragma unroll
      for (int r = 0; r < 4; ++r) {
        const int m = m0 + wr * 64 + i * 16 + lg * 4 + r;
        const float v = acc[i][j][r] + bv;
        if (OUT_MODE == 0) {
          const int b = m >> 11, t = m & 2047, h = n >> 6, d = n & 63;
          out[((size_t)(b * 16 + h) * 2048 + t) * 64 + d] = (OutT)v;
        } else if (OUT_MODE == 2) {
          const int b = m >> 11, t = m & 2047, h = n >> 6, d = n & 63;
          out[((size_t)(b * 16 + h) * 64 + d) * 2048 + t] = (OutT)v;
        } else {
          out[(size_t)m * N + n] = (OutT)v;
        }
      }
    }
  }
}

// ---------------------------------------------------------------------------
// Causal flash attention — round 5: double-buffered LDS staging + prefetch.
// Q,K in [B*H, T, D] bf16; Vt in [B*H, D, T] bf16 (pre-transposed).
// Output att_out in [B,T,C] bf16.
// Block: 256 thr = 4 waves; 64 q-rows/block, wave w owns rows [q0+16w,+16).
// Per kv-tile (64): K tile (64x128B) and V^T tile (64x128B) staged to LDS
// via global_load_lds with INVERSE-swizzled global source (rule 21); reads
// use byte ^= ((row&7)<<4). Tile t+1 staged BEFORE computing tile t
// (depth-1 prefetch, T3-minimum); ONE __syncthreads per tile.
// LDS: 2*16KB KV + 8KB P = 40960 B exactly -> 4 blocks/CU.
// qt reversed so longest blocks dispatch first (causal imbalance).
// ---------------------------------------------------------------------------
__global__ void attn_fwd(const bf16* __restrict__ Q, const bf16* __restrict__ Kk,
                         const bf16* __restrict__ Vt, bf16* __restrict__ attout) {
  __shared__ __align__(16) char KVs[2][16384];   // [buf]: K tile | V^T tile
  __shared__ __align__(16) char Ps[4][2048];     // per-wave P [16][128B] swz

  const int tid = threadIdx.x;
  const int wv = tid >> 6, lane = tid & 63;
  const int lr = lane & 15, lg = lane >> 4;
  const int q0 = (31 - blockIdx.x) * 64;         // longest-first
  const int bh = blockIdx.y;
  const size_t bhT = (size_t)bh * 2048;
  const bf16* Vh = Vt + (size_t)bh * 64 * 2048;  // [d][t]

  const int qrow = q0 + wv * 16 + lr;
  bf16x8 qf[2];
  qf[0] = *(const bf16x8*)(Q + (bhT + qrow) * 64 + lg * 8);
  qf[1] = *(const bf16x8*)(Q + (bhT + qrow) * 64 + 32 + lg * 8);

  f32x4 o[4] = {};
  float m_run[4] = {NEG_BIG, NEG_BIG, NEG_BIG, NEG_BIG};
  float l_run[4] = {0.f, 0.f, 0.f, 0.f};

  // Stage one kv-tile: linear LDS dest (wave-uniform base + lane*16),
  // inverse-swizzled global source.
  auto STAGE = [&](int buf, int kv0) {
#pragma unroll
    for (int rr = 0; rr < 2; ++rr) {
      const int c = rr * 256 + tid;             // chunk id = dest/16
      const int row = c >> 3, cc = c & 7;
      const int gcol = (cc ^ (row & 7)) * 8;    // elements
      gload_lds16(KVs[buf] + (rr * 256 + wv * 64) * 16,
                  Kk + (bhT + kv0 + row) * 64 + gcol);
      gload_lds16(KVs[buf] + 8192 + (rr * 256 + wv * 64) * 16,
                  Vh + (size_t)row * 2048 + kv0 + gcol);
    }
  };

  int cur = 0;
  STAGE(0, 0);
  __syncthreads();

  for (int kv0 = 0; kv0 <= q0; kv0 += 64) {
    if (kv0 + 64 <= q0) STAGE(cur ^ 1, kv0 + 64);  // prefetch next tile
    const char* Kb = KVs[cur];
    const char* Vb = KVs[cur] + 8192;

    // ---- S = Q . K^T from swizzled LDS ----
    f32x4 s[4] = {};
#pragma unroll
    for (int j = 0; j < 4; ++j) {
      const int n = j * 16 + lr;  // kv row
      const int sw = (n & 7) << 4;
      const bf16x8 kf0 = *(const bf16x8*)(Kb + n * 128 + ((lg * 16) ^ sw));
      s[j] = MFMA_16x16x32(qf[0], kf0, s[j]);
      const bf16x8 kf1 = *(const bf16x8*)(Kb + n * 128 + ((64 + lg * 16) ^ sw));
      s[j] = MFMA_16x16x32(qf[1], kf1, s[j]);
    }
#pragma unroll
    for (int j = 0; j < 4; ++j) s[j] *= 0.125f;  // 1/sqrt(64)

    if (kv0 == q0) {  // diagonal tile: causal mask
#pragma unroll
      for (int j = 0; j < 4; ++j) {
        const int colk = kv0 + j * 16 + lr;
#pragma unroll
        for (int r = 0; r < 4; ++r) {
          const int rowq = q0 + wv * 16 + lg * 4 + r;
          if (colk > rowq) s[j][r] = NEG_BIG;
        }
      }
    }

    // ---- online softmax: 4 q-rows/lane; cols over 16 lanes x 4 j ----
#pragma unroll
    for (int r = 0; r < 4; ++r) {
      float mx = fmaxf(fmaxf(s[0][r], s[1][r]), fmaxf(s[2][r], s[3][r]));
      mx = fmaxf(mx, __shfl_xor(mx, 1));
      mx = fmaxf(mx, __shfl_xor(mx, 2));
      mx = fmaxf(mx, __shfl_xor(mx, 4));
      mx = fmaxf(mx, __shfl_xor(mx, 8));
      const float mnew = fmaxf(m_run[r], mx);
      const float fac = __expf(m_run[r] - mnew);
      float rs = 0.f;
#pragma unroll
      for (int j = 0; j < 4; ++j) {
        const float p = __expf(s[j][r] - mnew);
        s[j][r] = p;
        rs += p;
      }
      rs += __shfl_xor(rs, 1);
      rs += __shfl_xor(rs, 2);
      rs += __shfl_xor(rs, 4);
      rs += __shfl_xor(rs, 8);
      l_run[r] = l_run[r] * fac + rs;
      m_run[r] = mnew;
#pragma unroll
      for (int jd = 0; jd < 4; ++jd) o[jd][r] *= fac;
    }

    // ---- P -> per-wave swizzled LDS (wave-synchronous, no barrier) ----
#pragma unroll
    for (int j = 0; j < 4; ++j)
#pragma unroll
      for (int r = 0; r < 4; ++r) {
        const int row = lg * 4 + r, col2 = (j * 16 + lr) * 2;
        *(bf16*)(Ps[wv] + row * 128 + (col2 ^ ((row & 7) << 4))) = (bf16)s[j][r];
      }
    const int swp = (lr & 7) << 4;
    const bf16x8 pf0 = *(const bf16x8*)(Ps[wv] + lr * 128 + ((lg * 16) ^ swp));
    const bf16x8 pf1 = *(const bf16x8*)(Ps[wv] + lr * 128 + ((64 + lg * 16) ^ swp));

    // ---- PV: o[q][d] += P[q][kv] * V[kv][d]; B-op from swizzled Vb ----
#pragma unroll
    for (int jd = 0; jd < 4; ++jd) {
      const int n = jd * 16 + lr;  // d
      const int sw = (n & 7) << 4;
      const bf16x8 vf0 = *(const bf16x8*)(Vb + n * 128 + ((lg * 16) ^ sw));
      o[jd] = MFMA_16x16x32(pf0, vf0, o[jd]);
      const bf16x8 vf1 = *(const bf16x8*)(Vb + n * 128 + ((64 + lg * 16) ^ sw));
      o[jd] = MFMA_16x16x32(pf1, vf1, o[jd]);
    }

    __syncthreads();   // drains vmcnt (prefetch landed) + lgkm, flips buffer
    cur ^= 1;
  }

  // ---- normalize + store att_out in [B,T,C] ----
  const int b = bh >> 4, h = bh & 15;
#pragma unroll
  for (int jd = 0; jd < 4; ++jd)
#pragma unroll
    for (int r = 0; r < 4; ++r) {
      const int rowq = q0 + wv * 16 + lg * 4 + r;
      const float ov = o[jd][r] / l_run[r];
      attout[((size_t)b * 2048 + rowq) * 1024 + h * 64 + jd * 16 + lr] = (bf16)ov;
    }
}

// ---------------------------------------------------------------------------
extern "C" void kernel_launch(void* const* d_in, const int* in_sizes, int n_in,
                              void* d_out, int out_size, void* d_ws, size_t ws_size,
                              hipStream_t stream) {
  const float* x   = (const float*)d_in[0];
  const float* xq  = (const float*)d_in[1];
  const float* Wq  = (const float*)d_in[2];
  const float* bq  = (const float*)d_in[3];
  const float* Wk  = (const float*)d_in[4];
  const float* bk  = (const float*)d_in[5];
  const float* Wv  = (const float*)d_in[6];
  const float* bv  = (const float*)d_in[7];
  const float* Wp  = (const float*)d_in[8];
  const float* bp  = (const float*)d_in[9];
  float* out = (float*)d_out;

  const size_t NTC = 4194304;  // B*T*C
  const size_t NW  = 1048576;  // C*C
  bf16* ws = (bf16*)d_ws;
  bf16* XQb = ws;
  bf16* Xb  = XQb + NTC;
  bf16* Wqb = Xb + NTC;
  bf16* Wkb = Wqb + NW;
  bf16* Wvb = Wkb + NW;
  bf16* Wpb = Wvb + NW;
  bf16* Qw  = Wpb + NW;              // [B*H, T, D]
  bf16* Kw  = Qw + NTC;
  bf16* Vtw = Kw + NTC;              // [B*H, D, T]
  bf16* Aw  = Vtw + NTC;             // [B, T, C]

  dim3 blk(256);
  f32_to_bf16<<<dim3((NTC / 8 + 255) / 256), blk, 0, stream>>>(xq, XQb, NTC / 8);
  f32_to_bf16<<<dim3((NTC / 8 + 255) / 256), blk, 0, stream>>>(x, Xb, NTC / 8);
  f32_to_bf16<<<dim3((NW / 8 + 255) / 256), blk, 0, stream>>>(Wq, Wqb, NW / 8);
  f32_to_bf16<<<dim3((NW / 8 + 255) / 256), blk, 0, stream>>>(Wk, Wkb, NW / 8);
  f32_to_bf16<<<dim3((NW / 8 + 255) / 256), blk, 0, stream>>>(Wv, Wvb, NW / 8);
  f32_to_bf16<<<dim3((NW / 8 + 255) / 256), blk, 0, stream>>>(Wp, Wpb, NW / 8);

  gemm_bt<0, bf16><<<dim3(8, 32), blk, 0, stream>>>(XQb, Wqb, bq, Qw, 4096, 1024, 1024);
  gemm_bt<0, bf16><<<dim3(8, 32), blk, 0, stream>>>(Xb,  Wkb, bk, Kw, 4096, 1024, 1024);
  gemm_bt<2, bf16><<<dim3(8, 32), blk, 0, stream>>>(Xb,  Wvb, bv, Vtw, 4096, 1024, 1024);
  attn_fwd<<<dim3(32, 32), blk, 0, stream>>>(Qw, Kw, Vtw, Aw);
  gemm_bt<1, float><<<dim3(8, 32), blk, 0, stream>>>(Aw, Wpb, bp, out, 4096, 1024, 1024);
}

// Round 6
// 163.743 us; speedup vs baseline: 2.1033x; 1.3892x over previous
//
#include <hip/hip_runtime.h>

typedef __bf16 bf16;
typedef __attribute__((ext_vector_type(8))) __bf16 bf16x8;
typedef __attribute__((ext_vector_type(4))) float f32x4;
typedef __attribute__((ext_vector_type(16))) float f32x16;
typedef __attribute__((ext_vector_type(4))) unsigned u32x4;

#define MFMA16(a, b, c) __builtin_amdgcn_mfma_f32_16x16x32_bf16((a), (b), (c), 0, 0, 0)
#define MFMA32(a, b, c) __builtin_amdgcn_mfma_f32_32x32x16_bf16((a), (b), (c), 0, 0, 0)
#define NEG_BIG (-1e30f)
#define SCL_LOG2 0.18033688011112042f  /* log2(e)/sqrt(64) */

__device__ __forceinline__ void gload_lds16(void* lds, const void* g) {
  __builtin_amdgcn_global_load_lds(
      (const __attribute__((address_space(1))) void*)g,
      (__attribute__((address_space(3))) void*)lds, 16, 0, 0);
}

__device__ __forceinline__ unsigned pk2(float x, float y) {
  const unsigned short a = __builtin_bit_cast(unsigned short, (bf16)x);
  const unsigned short b = __builtin_bit_cast(unsigned short, (bf16)y);
  return (unsigned)a | ((unsigned)b << 16);
}

// ---------------------------------------------------------------------------
// Fused f32 -> bf16 conversion for all 6 tensors (1 launch).
// Chunk = 8 elements. s0,s1: 524288 chunks; s2..s5: 131072 chunks each.
// ---------------------------------------------------------------------------
__global__ void cvt6(const float* __restrict__ s0, const float* __restrict__ s1,
                     const float* __restrict__ s2, const float* __restrict__ s3,
                     const float* __restrict__ s4, const float* __restrict__ s5,
                     bf16* __restrict__ d0, bf16* __restrict__ d1,
                     bf16* __restrict__ d2, bf16* __restrict__ d3,
                     bf16* __restrict__ d4, bf16* __restrict__ d5) {
  const int c = blockIdx.x * blockDim.x + threadIdx.x;
  if (c >= 1572864) return;
  const float* s; bf16* d; int off;
  if (c < 524288)        { s = s0; d = d0; off = c; }
  else if (c < 1048576)  { s = s1; d = d1; off = c - 524288; }
  else {
    const int c2 = c - 1048576, seg = c2 >> 17;
    off = c2 & 131071;
    s = seg == 0 ? s2 : seg == 1 ? s3 : seg == 2 ? s4 : s5;
    d = seg == 0 ? d2 : seg == 1 ? d3 : seg == 2 ? d4 : d5;
  }
  const float4 a = ((const float4*)s)[off * 2 + 0];
  const float4 b = ((const float4*)s)[off * 2 + 1];
  bf16x8 o;
  o[0] = (bf16)a.x; o[1] = (bf16)a.y; o[2] = (bf16)a.z; o[3] = (bf16)a.w;
  o[4] = (bf16)b.x; o[5] = (bf16)b.y; o[6] = (bf16)b.z; o[7] = (bf16)b.w;
  ((bf16x8*)d)[off] = o;
}

// ---------------------------------------------------------------------------
// GEMM (BT): out = A[M,K] . W[N,K]^T + bias[N]   (m97 template)
// OUT_MODE 0: bf16, head layout ((b*16+h)*2048+t)*64+d            (Q)
// OUT_MODE 1: f32, plain row-major [M,N]                          (final proj)
// ---------------------------------------------------------------------------
template <int OUT_MODE, typename OutT>
__global__ void gemm_bt(const bf16* __restrict__ A, const bf16* __restrict__ W,
                        const float* __restrict__ bias, OutT* __restrict__ out,
                        int M, int N, int K) {
  __shared__ __align__(16) bf16 As[128 * 32];
  __shared__ __align__(16) bf16 Bs[128 * 32];
  const int tid = threadIdx.x;
  const int wv = tid >> 6, lane = tid & 63;
  const int wr = wv >> 1, wc = wv & 1;
  const int lr = lane & 15, lg = lane >> 4;
  const int m0 = blockIdx.y * 128, n0 = blockIdx.x * 128;

  f32x4 acc[4][4] = {};

  for (int k0 = 0; k0 < K; k0 += 32) {
    __syncthreads();
#pragma unroll
    for (int j = 0; j < 2; ++j) {
      const int e8 = (j * 256 + tid) * 8;
      const int row = e8 >> 5, col = e8 & 31;
      gload_lds16(As + (size_t)(j * 256 + wv * 64) * 8,
                  A + (size_t)(m0 + row) * K + k0 + col);
      gload_lds16(Bs + (size_t)(j * 256 + wv * 64) * 8,
                  W + (size_t)(n0 + row) * K + k0 + col);
    }
    __syncthreads();
    bf16x8 af[4], bfr[4];
#pragma unroll
    for (int i = 0; i < 4; ++i)
      af[i] = *(const bf16x8*)&As[(wr * 64 + i * 16 + lr) * 32 + lg * 8];
#pragma unroll
    for (int j = 0; j < 4; ++j)
      bfr[j] = *(const bf16x8*)&Bs[(wc * 64 + j * 16 + lr) * 32 + lg * 8];
#pragma unroll
    for (int i = 0; i < 4; ++i)
#pragma unroll
      for (int j = 0; j < 4; ++j)
        acc[i][j] = MFMA16(af[i], bfr[j], acc[i][j]);
  }

#pragma unroll
  for (int j = 0; j < 4; ++j) {
    const int n = n0 + wc * 64 + j * 16 + lr;
    const float bv = bias[n];
#pragma unroll
    for (int i = 0; i < 4; ++i) {
#pragma unroll
      for (int r = 0; r < 4; ++r) {
        const int m = m0 + wr * 64 + i * 16 + lg * 4 + r;
        const float v = acc[i][j][r] + bv;
        if (OUT_MODE == 0) {
          const int b = m >> 11, t = m & 2047, h = n >> 6, d = n & 63;
          out[((size_t)(b * 16 + h) * 2048 + t) * 64 + d] = (OutT)v;
        } else {
          out[(size_t)m * N + n] = (OutT)v;
        }
      }
    }
  }
}

// ---------------------------------------------------------------------------
// Merged K+V projection: one launch, 512 blocks (2/CU).
// blockIdx.x 0..7  -> K half (Wk, bk) -> Kout head layout [bh][t][d]
// blockIdx.x 8..15 -> V half (Wv, bv) -> Vtout transposed [bh][d][t]
// ---------------------------------------------------------------------------
__global__ void gemm_kv(const bf16* __restrict__ A,
                        const bf16* __restrict__ Wk, const bf16* __restrict__ Wv,
                        const float* __restrict__ bk, const float* __restrict__ bv,
                        bf16* __restrict__ Kout, bf16* __restrict__ Vtout) {
  __shared__ __align__(16) bf16 As[128 * 32];
  __shared__ __align__(16) bf16 Bs[128 * 32];
  const int tid = threadIdx.x;
  const int wv = tid >> 6, lane = tid & 63;
  const int wr = wv >> 1, wc = wv & 1;
  const int lr = lane & 15, lg = lane >> 4;
  const bool isV = blockIdx.x >= 8;
  const int n0 = (blockIdx.x & 7) * 128;
  const int m0 = blockIdx.y * 128;
  const bf16* __restrict__ W = isV ? Wv : Wk;
  const float* __restrict__ bias = isV ? bv : bk;
  const int K = 1024;

  f32x4 acc[4][4] = {};

  for (int k0 = 0; k0 < K; k0 += 32) {
    __syncthreads();
#pragma unroll
    for (int j = 0; j < 2; ++j) {
      const int e8 = (j * 256 + tid) * 8;
      const int row = e8 >> 5, col = e8 & 31;
      gload_lds16(As + (size_t)(j * 256 + wv * 64) * 8,
                  A + (size_t)(m0 + row) * K + k0 + col);
      gload_lds16(Bs + (size_t)(j * 256 + wv * 64) * 8,
                  W + (size_t)(n0 + row) * K + k0 + col);
    }
    __syncthreads();
    bf16x8 af[4], bfr[4];
#pragma unroll
    for (int i = 0; i < 4; ++i)
      af[i] = *(const bf16x8*)&As[(wr * 64 + i * 16 + lr) * 32 + lg * 8];
#pragma unroll
    for (int j = 0; j < 4; ++j)
      bfr[j] = *(const bf16x8*)&Bs[(wc * 64 + j * 16 + lr) * 32 + lg * 8];
#pragma unroll
    for (int i = 0; i < 4; ++i)
#pragma unroll
      for (int j = 0; j < 4; ++j)
        acc[i][j] = MFMA16(af[i], bfr[j], acc[i][j]);
  }

#pragma unroll
  for (int j = 0; j < 4; ++j) {
    const int n = n0 + wc * 64 + j * 16 + lr;  // 0..1023 within half
    const float bvv = bias[n];
    const int h = n >> 6, d = n & 63;
#pragma unroll
    for (int i = 0; i < 4; ++i) {
#pragma unroll
      for (int r = 0; r < 4; ++r) {
        const int m = m0 + wr * 64 + i * 16 + lg * 4 + r;
        const float v = acc[i][j][r] + bvv;
        const int b = m >> 11, t = m & 2047;
        if (!isV) Kout[((size_t)(b * 16 + h) * 2048 + t) * 64 + d] = (bf16)v;
        else      Vtout[((size_t)(b * 16 + h) * 64 + d) * 2048 + t] = (bf16)v;
      }
    }
  }
}

// ---------------------------------------------------------------------------
// Causal flash attention — round 6: 32x32 swapped-operand, lane-local softmax.
// Q,K in [B*H, T, D] bf16; Vt in [B*H, D, T] bf16 (pre-transposed).
// 1D grid of 512 blocks: qt = 15 - (bid>>5) (longest-first), bh = bid&31.
// Block = 4 waves x 32 q-rows = 128 rows. Wave computes, per kv-tile (64):
//   S^T = mfma32(K, Q)  -> lane q31 holds S[kv 0..63][q] in 32 f32 regs
//   softmax: in-register trees + ONE __shfl_xor(,32); m/l scalar per lane
//   P->bf16 pack (16 pk2 + 8 shfl_xor(32), T12 pattern)
//   O^T = mfma32(V^T, P^T) -> rescale factor lane-local
// K/V^T staged to LDS double-buffered via global_load_lds w/ pre-swizzled
// source (round-5-verified STAGE); depth-1 prefetch; one barrier per tile.
// ---------------------------------------------------------------------------
__global__ void attn_fwd(const bf16* __restrict__ Q, const bf16* __restrict__ Kk,
                         const bf16* __restrict__ Vt, bf16* __restrict__ attout) {
  __shared__ __align__(16) char Ks[2][8192];   // [kv 64][d swz 128B]
  __shared__ __align__(16) char Vs[2][8192];   // [d 64][kv swz 128B]

  const int tid = threadIdx.x;
  const int wv = tid >> 6, lane = tid & 63;
  const int q31 = lane & 31, hi = lane >> 5, l7 = lane & 7;
  const int bid = blockIdx.x;
  const int qt = 15 - (bid >> 5), bh = bid & 31;
  const int q0 = qt * 128;
  const int qs = q0 + wv * 32;        // wave's q base
  const int qa = qs + q31;            // lane's absolute q row
  const size_t bhT = (size_t)bh * 2048;
  const bf16* Vh = Vt + (size_t)bh * 64 * 2048;

  // Q as B-operand frags: qf[kw] = Q[qa][16kw + 8hi + 0..7]
  bf16x8 qf[4];
#pragma unroll
  for (int kw = 0; kw < 4; ++kw)
    qf[kw] = *(const bf16x8*)(Q + (bhT + qa) * 64 + kw * 16 + hi * 8);

  f32x16 O0 = {}, O1 = {};   // O^T[d 0..31 / 32..63][q=q31]
  float m2 = NEG_BIG, l = 0.f;

  const int nt = q0 / 64 + 2;

  auto STAGE = [&](int buf, int kv0) {
#pragma unroll
    for (int rr = 0; rr < 2; ++rr) {
      const int c = rr * 256 + tid;
      const int row = c >> 3, cc = c & 7;
      const int gcol = (cc ^ (row & 7)) * 8;
      gload_lds16(Ks[buf] + (rr * 256 + wv * 64) * 16,
                  Kk + (bhT + kv0 + row) * 64 + gcol);
      gload_lds16(Vs[buf] + (rr * 256 + wv * 64) * 16,
                  Vh + (size_t)row * 2048 + kv0 + gcol);
    }
  };

  int cur = 0;
  STAGE(0, 0);
  __syncthreads();

  for (int it = 0; it < nt; ++it) {
    const int kv0 = it * 64;
    if (it + 1 < nt) STAGE(cur ^ 1, (it + 1) * 64);

    if (kv0 <= qs + 31) {   // wave-uniform: skip fully-masked tiles
      // ---- S^T = K . Q^T ----
      f32x16 S0 = {}, S1 = {};
#pragma unroll
      for (int kw = 0; kw < 4; ++kw) {
        const int cb = (32 * kw + 16 * hi) ^ (l7 << 4);
        const bf16x8 k0 = *(const bf16x8*)(Ks[cur] + q31 * 128 + cb);
        const bf16x8 k1 = *(const bf16x8*)(Ks[cur] + (32 + q31) * 128 + cb);
        S0 = MFMA32(k0, qf[kw], S0);
        S1 = MFMA32(k1, qf[kw], S1);
      }

      // ---- to log2 domain + causal mask ----
      float p[32];
#pragma unroll
      for (int r = 0; r < 16; ++r) {
        p[r]      = S0[r] * SCL_LOG2;
        p[16 + r] = S1[r] * SCL_LOG2;
      }
      if (kv0 + 63 > qs) {
#pragma unroll
        for (int a = 0; a < 2; ++a)
#pragma unroll
          for (int r = 0; r < 16; ++r) {
            const int kva = kv0 + a * 32 + (r & 3) + 8 * (r >> 2) + 4 * hi;
            if (kva > qa) p[a * 16 + r] = NEG_BIG;
          }
      }

      // ---- lane-local online softmax (row lives in this lane + lane^32) ----
      float w16[16];
#pragma unroll
      for (int i = 0; i < 16; ++i) w16[i] = fmaxf(p[i], p[i + 16]);
#pragma unroll
      for (int i = 0; i < 8; ++i) w16[i] = fmaxf(w16[i], w16[i + 8]);
#pragma unroll
      for (int i = 0; i < 4; ++i) w16[i] = fmaxf(w16[i], w16[i + 4]);
      float mx = fmaxf(fmaxf(w16[0], w16[1]), fmaxf(w16[2], w16[3]));
      mx = fmaxf(mx, __shfl_xor(mx, 32));
      const float mnew = fmaxf(m2, mx);
      const float fac = exp2f(m2 - mnew);   // 0 on first computed tile
#pragma unroll
      for (int i = 0; i < 32; ++i) p[i] = exp2f(p[i] - mnew);
      float s16[16];
#pragma unroll
      for (int i = 0; i < 16; ++i) s16[i] = p[i] + p[i + 16];
#pragma unroll
      for (int i = 0; i < 8; ++i) s16[i] += s16[i + 8];
#pragma unroll
      for (int i = 0; i < 4; ++i) s16[i] += s16[i + 4];
      float rs = (s16[0] + s16[1]) + (s16[2] + s16[3]);
      rs += __shfl_xor(rs, 32);
      l = l * fac + rs;
      m2 = mnew;
#pragma unroll
      for (int r = 0; r < 16; ++r) { O0[r] *= fac; O1[r] *= fac; }

      // ---- pack P rows -> B-operand frags (static indices; T12 pattern) ----
      bf16x8 pf[4];
#pragma unroll
      for (int ks = 0; ks < 4; ++ks) {
        const int base = 16 * (ks >> 1) + 8 * (ks & 1);
        const unsigned g0 = pk2(p[base + 0], p[base + 1]);
        const unsigned g1 = pk2(p[base + 2], p[base + 3]);
        const unsigned g2 = pk2(p[base + 4], p[base + 5]);
        const unsigned g3 = pk2(p[base + 6], p[base + 7]);
        const unsigned e0 = __shfl_xor(hi ? g0 : g2, 32);
        const unsigned e1 = __shfl_xor(hi ? g1 : g3, 32);
        u32x4 w4;
        w4[0] = hi ? e0 : g0;
        w4[1] = hi ? e1 : g1;
        w4[2] = hi ? g2 : e0;
        w4[3] = hi ? g3 : e1;
        pf[ks] = __builtin_bit_cast(bf16x8, w4);
      }

      // ---- O^T += V^T . P^T ----
#pragma unroll
      for (int ks = 0; ks < 4; ++ks) {
        const int cb = (32 * ks + 16 * hi) ^ (l7 << 4);
        const bf16x8 v0 = *(const bf16x8*)(Vs[cur] + q31 * 128 + cb);
        const bf16x8 v1 = *(const bf16x8*)(Vs[cur] + (32 + q31) * 128 + cb);
        O0 = MFMA32(v0, pf[ks], O0);
        O1 = MFMA32(v1, pf[ks], O1);
      }
    }
    __syncthreads();
    cur ^= 1;
  }

  // ---- epilogue: normalize + store [B,T,C] ----
  const int b = bh >> 4, h = bh & 15;
  const float inv = 1.f / l;
  bf16* orow = attout + ((size_t)b * 2048 + qa) * 1024 + h * 64;
#pragma unroll
  for (int r = 0; r < 16; ++r) {
    const int dd = (r & 3) + 8 * (r >> 2) + 4 * hi;
    orow[dd]      = (bf16)(O0[r] * inv);
    orow[32 + dd] = (bf16)(O1[r] * inv);
  }
}

// ---------------------------------------------------------------------------
extern "C" void kernel_launch(void* const* d_in, const int* in_sizes, int n_in,
                              void* d_out, int out_size, void* d_ws, size_t ws_size,
                              hipStream_t stream) {
  const float* x   = (const float*)d_in[0];
  const float* xq  = (const float*)d_in[1];
  const float* Wq  = (const float*)d_in[2];
  const float* bq  = (const float*)d_in[3];
  const float* Wk  = (const float*)d_in[4];
  const float* bk  = (const float*)d_in[5];
  const float* Wv  = (const float*)d_in[6];
  const float* bv  = (const float*)d_in[7];
  const float* Wp  = (const float*)d_in[8];
  const float* bp  = (const float*)d_in[9];
  float* out = (float*)d_out;

  const size_t NTC = 4194304;  // B*T*C
  const size_t NW  = 1048576;  // C*C
  bf16* ws = (bf16*)d_ws;
  bf16* XQb = ws;
  bf16* Xb  = XQb + NTC;
  bf16* Wqb = Xb + NTC;
  bf16* Wkb = Wqb + NW;
  bf16* Wvb = Wkb + NW;
  bf16* Wpb = Wvb + NW;
  bf16* Qw  = Wpb + NW;              // [B*H, T, D]
  bf16* Kw  = Qw + NTC;
  bf16* Vtw = Kw + NTC;              // [B*H, D, T]
  bf16* Aw  = Vtw + NTC;             // [B, T, C]

  dim3 blk(256);
  cvt6<<<dim3(6144), blk, 0, stream>>>(xq, x, Wq, Wk, Wv, Wp,
                                       XQb, Xb, Wqb, Wkb, Wvb, Wpb);

  gemm_bt<0, bf16><<<dim3(8, 32), blk, 0, stream>>>(XQb, Wqb, bq, Qw, 4096, 1024, 1024);
  gemm_kv<<<dim3(16, 32), blk, 0, stream>>>(Xb, Wkb, Wvb, bk, bv, Kw, Vtw);
  attn_fwd<<<dim3(512), blk, 0, stream>>>(Qw, Kw, Vtw, Aw);
  gemm_bt<1, float><<<dim3(8, 32), blk, 0, stream>>>(Aw, Wpb, bp, out, 4096, 1024, 1024);
}

// Round 7
// 144.491 us; speedup vs baseline: 2.3836x; 1.1332x over previous
//
#include <hip/hip_runtime.h>

typedef __bf16 bf16;
typedef __attribute__((ext_vector_type(8))) __bf16 bf16x8;
typedef __attribute__((ext_vector_type(4))) float f32x4;
typedef __attribute__((ext_vector_type(16))) float f32x16;
typedef __attribute__((ext_vector_type(4))) unsigned u32x4;

#define MFMA16(a, b, c) __builtin_amdgcn_mfma_f32_16x16x32_bf16((a), (b), (c), 0, 0, 0)
#define MFMA32(a, b, c) __builtin_amdgcn_mfma_f32_32x32x16_bf16((a), (b), (c), 0, 0, 0)
#define NEG_BIG (-1e30f)
#define SCL_LOG2 0.18033688011112042f  /* log2(e)/sqrt(64) */

__device__ __forceinline__ void gload_lds16(void* lds, const void* g) {
  __builtin_amdgcn_global_load_lds(
      (const __attribute__((address_space(1))) void*)g,
      (__attribute__((address_space(3))) void*)lds, 16, 0, 0);
}

__device__ __forceinline__ unsigned pk2(float x, float y) {
  const unsigned short a = __builtin_bit_cast(unsigned short, (bf16)x);
  const unsigned short b = __builtin_bit_cast(unsigned short, (bf16)y);
  return (unsigned)a | ((unsigned)b << 16);
}

// ---------------------------------------------------------------------------
// Fused f32 -> bf16 conversion for all 6 tensors (1 launch).
// ---------------------------------------------------------------------------
__global__ void cvt6(const float* __restrict__ s0, const float* __restrict__ s1,
                     const float* __restrict__ s2, const float* __restrict__ s3,
                     const float* __restrict__ s4, const float* __restrict__ s5,
                     bf16* __restrict__ d0, bf16* __restrict__ d1,
                     bf16* __restrict__ d2, bf16* __restrict__ d3,
                     bf16* __restrict__ d4, bf16* __restrict__ d5) {
  const int c = blockIdx.x * blockDim.x + threadIdx.x;
  if (c >= 1572864) return;
  const float* s; bf16* d; int off;
  if (c < 524288)        { s = s0; d = d0; off = c; }
  else if (c < 1048576)  { s = s1; d = d1; off = c - 524288; }
  else {
    const int c2 = c - 1048576, seg = c2 >> 17;
    off = c2 & 131071;
    s = seg == 0 ? s2 : seg == 1 ? s3 : seg == 2 ? s4 : s5;
    d = seg == 0 ? d2 : seg == 1 ? d3 : seg == 2 ? d4 : d5;
  }
  const float4 a = ((const float4*)s)[off * 2 + 0];
  const float4 b = ((const float4*)s)[off * 2 + 1];
  bf16x8 o;
  o[0] = (bf16)a.x; o[1] = (bf16)a.y; o[2] = (bf16)a.z; o[3] = (bf16)a.w;
  o[4] = (bf16)b.x; o[5] = (bf16)b.y; o[6] = (bf16)b.z; o[7] = (bf16)b.w;
  ((bf16x8*)d)[off] = o;
}

// ---------------------------------------------------------------------------
// Merged Q+K+V projection: 768 blocks (3/CU).
//  blockIdx.x>>3: 0 -> Q = XQ.Wq^T+bq  (head layout [bh][t][d])
//                 1 -> K = X.Wk^T+bk   (head layout [bh][t][d])
//                 2 -> V = X.Wv^T+bv   (TRANSPOSED [bh][d][t])
// Body = verified m97 128x128/BK=32 template.
// ---------------------------------------------------------------------------
__global__ void gemm_qkv(const bf16* __restrict__ XQ, const bf16* __restrict__ X,
                         const bf16* __restrict__ Wq, const bf16* __restrict__ Wk,
                         const bf16* __restrict__ Wv,
                         const float* __restrict__ bq, const float* __restrict__ bk,
                         const float* __restrict__ bv,
                         bf16* __restrict__ Qo, bf16* __restrict__ Ko,
                         bf16* __restrict__ Vto) {
  __shared__ __align__(16) bf16 As[128 * 32];
  __shared__ __align__(16) bf16 Bs[128 * 32];
  const int tid = threadIdx.x;
  const int wv = tid >> 6, lane = tid & 63;
  const int wr = wv >> 1, wc = wv & 1;
  const int lr = lane & 15, lg = lane >> 4;
  const int seg = blockIdx.x >> 3;
  const int n0 = (blockIdx.x & 7) * 128;
  const int m0 = blockIdx.y * 128;
  const bf16* __restrict__ A = seg == 0 ? XQ : X;
  const bf16* __restrict__ W = seg == 0 ? Wq : seg == 1 ? Wk : Wv;
  const float* __restrict__ bias = seg == 0 ? bq : seg == 1 ? bk : bv;
  const int K = 1024;

  f32x4 acc[4][4] = {};

  for (int k0 = 0; k0 < K; k0 += 32) {
    __syncthreads();
#pragma unroll
    for (int j = 0; j < 2; ++j) {
      const int e8 = (j * 256 + tid) * 8;
      const int row = e8 >> 5, col = e8 & 31;
      gload_lds16(As + (size_t)(j * 256 + wv * 64) * 8,
                  A + (size_t)(m0 + row) * K + k0 + col);
      gload_lds16(Bs + (size_t)(j * 256 + wv * 64) * 8,
                  W + (size_t)(n0 + row) * K + k0 + col);
    }
    __syncthreads();
    bf16x8 af[4], bfr[4];
#pragma unroll
    for (int i = 0; i < 4; ++i)
      af[i] = *(const bf16x8*)&As[(wr * 64 + i * 16 + lr) * 32 + lg * 8];
#pragma unroll
    for (int j = 0; j < 4; ++j)
      bfr[j] = *(const bf16x8*)&Bs[(wc * 64 + j * 16 + lr) * 32 + lg * 8];
#pragma unroll
    for (int i = 0; i < 4; ++i)
#pragma unroll
      for (int j = 0; j < 4; ++j)
        acc[i][j] = MFMA16(af[i], bfr[j], acc[i][j]);
  }

#pragma unroll
  for (int j = 0; j < 4; ++j) {
    const int n = n0 + wc * 64 + j * 16 + lr;
    const float bvv = bias[n];
    const int h = n >> 6, d = n & 63;
#pragma unroll
    for (int i = 0; i < 4; ++i) {
#pragma unroll
      for (int r = 0; r < 4; ++r) {
        const int m = m0 + wr * 64 + i * 16 + lg * 4 + r;
        const float v = acc[i][j][r] + bvv;
        const int b = m >> 11, t = m & 2047;
        if (seg == 0)      Qo[((size_t)(b * 16 + h) * 2048 + t) * 64 + d] = (bf16)v;
        else if (seg == 1) Ko[((size_t)(b * 16 + h) * 2048 + t) * 64 + d] = (bf16)v;
        else               Vto[((size_t)(b * 16 + h) * 64 + d) * 2048 + t] = (bf16)v;
      }
    }
  }
}

// ---------------------------------------------------------------------------
// Final projection GEMM: out = A[M,K].W[N,K]^T + bias, f32 out row-major.
// BN=64 -> grid (N/64, M/128) = 512 blocks (2/CU).
// ---------------------------------------------------------------------------
template <int BN>
__global__ void gemm_out(const bf16* __restrict__ A, const bf16* __restrict__ W,
                         const float* __restrict__ bias, float* __restrict__ out,
                         int M, int N, int K) {
  __shared__ __align__(16) bf16 As[128 * 32];
  __shared__ __align__(16) bf16 Bs[BN * 32];
  constexpr int NF = BN / 32;       // B-frags / N-tiles per wave
  const int tid = threadIdx.x;
  const int wv = tid >> 6, lane = tid & 63;
  const int wr = wv >> 1, wc = wv & 1;
  const int lr = lane & 15, lg = lane >> 4;
  const int m0 = blockIdx.y * 128, n0 = blockIdx.x * BN;

  f32x4 acc[4][NF] = {};

  for (int k0 = 0; k0 < K; k0 += 32) {
    __syncthreads();
#pragma unroll
    for (int j = 0; j < 2; ++j) {
      const int e8 = (j * 256 + tid) * 8;
      const int row = e8 >> 5, col = e8 & 31;
      gload_lds16(As + (size_t)(j * 256 + wv * 64) * 8,
                  A + (size_t)(m0 + row) * K + k0 + col);
    }
#pragma unroll
    for (int j = 0; j < BN / 64; ++j) {
      const int e8 = (j * 256 + tid) * 8;
      const int row = e8 >> 5, col = e8 & 31;
      gload_lds16(Bs + (size_t)(j * 256 + wv * 64) * 8,
                  W + (size_t)(n0 + row) * K + k0 + col);
    }
    __syncthreads();
    bf16x8 af[4], bfr[NF];
#pragma unroll
    for (int i = 0; i < 4; ++i)
      af[i] = *(const bf16x8*)&As[(wr * 64 + i * 16 + lr) * 32 + lg * 8];
#pragma unroll
    for (int j = 0; j < NF; ++j)
      bfr[j] = *(const bf16x8*)&Bs[(wc * (BN / 2) + j * 16 + lr) * 32 + lg * 8];
#pragma unroll
    for (int i = 0; i < 4; ++i)
#pragma unroll
      for (int j = 0; j < NF; ++j)
        acc[i][j] = MFMA16(af[i], bfr[j], acc[i][j]);
  }

#pragma unroll
  for (int j = 0; j < NF; ++j) {
    const int n = n0 + wc * (BN / 2) + j * 16 + lr;
    const float bv = bias[n];
#pragma unroll
    for (int i = 0; i < 4; ++i) {
#pragma unroll
      for (int r = 0; r < 4; ++r) {
        const int m = m0 + wr * 64 + i * 16 + lg * 4 + r;
        out[(size_t)m * N + n] = acc[i][j][r] + bv;
      }
    }
  }
}

// ---------------------------------------------------------------------------
// Causal flash attention — round 7: balanced grid + defer-max + setprio.
// Structure (round-6-verified): 32x32 swapped-operand, lane-local softmax,
// K/V^T double-buffered LDS staging w/ pre-swizzled gload_lds source.
// Grid 512: bid<256 -> qt=15-(bid>>5); bid>=256 -> qt=(bid-256)>>5, so the
// two blocks per CU sum to ~34 kv-tiles (load balance).
// ---------------------------------------------------------------------------
__global__ void attn_fwd(const bf16* __restrict__ Q, const bf16* __restrict__ Kk,
                         const bf16* __restrict__ Vt, bf16* __restrict__ attout) {
  __shared__ __align__(16) char Ks[2][8192];   // [kv 64][d swz 128B]
  __shared__ __align__(16) char Vs[2][8192];   // [d 64][kv swz 128B]

  const int tid = threadIdx.x;
  const int wv = tid >> 6, lane = tid & 63;
  const int q31 = lane & 31, hi = lane >> 5, l7 = lane & 7;
  const int bid = blockIdx.x;
  const int qt = (bid < 256) ? (15 - (bid >> 5)) : ((bid - 256) >> 5);
  const int bh = bid & 31;
  const int q0 = qt * 128;
  const int qs = q0 + wv * 32;        // wave's q base
  const int qa = qs + q31;            // lane's absolute q row
  const size_t bhT = (size_t)bh * 2048;
  const bf16* Vh = Vt + (size_t)bh * 64 * 2048;

  // Q as B-operand frags: qf[kw] = Q[qa][16kw + 8hi + 0..7]
  bf16x8 qf[4];
#pragma unroll
  for (int kw = 0; kw < 4; ++kw)
    qf[kw] = *(const bf16x8*)(Q + (bhT + qa) * 64 + kw * 16 + hi * 8);

  f32x16 O0 = {}, O1 = {};   // O^T[d 0..31 / 32..63][q=q31]
  float m2 = NEG_BIG, l = 0.f;

  const int nt = q0 / 64 + 2;

  auto STAGE = [&](int buf, int kv0) {
#pragma unroll
    for (int rr = 0; rr < 2; ++rr) {
      const int c = rr * 256 + tid;
      const int row = c >> 3, cc = c & 7;
      const int gcol = (cc ^ (row & 7)) * 8;
      gload_lds16(Ks[buf] + (rr * 256 + wv * 64) * 16,
                  Kk + (bhT + kv0 + row) * 64 + gcol);
      gload_lds16(Vs[buf] + (rr * 256 + wv * 64) * 16,
                  Vh + (size_t)row * 2048 + kv0 + gcol);
    }
  };

  int cur = 0;
  STAGE(0, 0);
  __syncthreads();

  for (int it = 0; it < nt; ++it) {
    const int kv0 = it * 64;
    if (it + 1 < nt) STAGE(cur ^ 1, (it + 1) * 64);

    if (kv0 <= qs + 31) {   // wave-uniform: skip fully-masked tiles
      // ---- S^T = K . Q^T ----
      f32x16 S0 = {}, S1 = {};
      __builtin_amdgcn_s_setprio(1);
#pragma unroll
      for (int kw = 0; kw < 4; ++kw) {
        const int cb = (32 * kw + 16 * hi) ^ (l7 << 4);
        const bf16x8 k0 = *(const bf16x8*)(Ks[cur] + q31 * 128 + cb);
        const bf16x8 k1 = *(const bf16x8*)(Ks[cur] + (32 + q31) * 128 + cb);
        S0 = MFMA32(k0, qf[kw], S0);
        S1 = MFMA32(k1, qf[kw], S1);
      }
      __builtin_amdgcn_s_setprio(0);

      // ---- to log2 domain + causal mask ----
      float p[32];
#pragma unroll
      for (int r = 0; r < 16; ++r) {
        p[r]      = S0[r] * SCL_LOG2;
        p[16 + r] = S1[r] * SCL_LOG2;
      }
      if (kv0 + 63 > qs) {
#pragma unroll
        for (int a = 0; a < 2; ++a)
#pragma unroll
          for (int r = 0; r < 16; ++r) {
            const int kva = kv0 + a * 32 + (r & 3) + 8 * (r >> 2) + 4 * hi;
            if (kva > qa) p[a * 16 + r] = NEG_BIG;
          }
      }

      // ---- lane-local online softmax with defer-max (T13, THR=8) ----
      float w16[16];
#pragma unroll
      for (int i = 0; i < 16; ++i) w16[i] = fmaxf(p[i], p[i + 16]);
#pragma unroll
      for (int i = 0; i < 8; ++i) w16[i] = fmaxf(w16[i], w16[i + 8]);
#pragma unroll
      for (int i = 0; i < 4; ++i) w16[i] = fmaxf(w16[i], w16[i + 4]);
      float mx = fmaxf(fmaxf(w16[0], w16[1]), fmaxf(w16[2], w16[3]));
      mx = fmaxf(mx, __shfl_xor(mx, 32));
      if (!__all(mx - m2 <= 8.f)) {          // rescale only on real growth
        const float mnew = fmaxf(m2, mx);
        const float fac = exp2f(m2 - mnew);  // 0 on first computed tile
        l *= fac;
#pragma unroll
        for (int r = 0; r < 16; ++r) { O0[r] *= fac; O1[r] *= fac; }
        m2 = mnew;
      }
#pragma unroll
      for (int i = 0; i < 32; ++i) p[i] = exp2f(p[i] - m2);
      float s16[16];
#pragma unroll
      for (int i = 0; i < 16; ++i) s16[i] = p[i] + p[i + 16];
#pragma unroll
      for (int i = 0; i < 8; ++i) s16[i] += s16[i + 8];
#pragma unroll
      for (int i = 0; i < 4; ++i) s16[i] += s16[i + 4];
      float rs = (s16[0] + s16[1]) + (s16[2] + s16[3]);
      rs += __shfl_xor(rs, 32);
      l += rs;

      // ---- pack P rows -> B-operand frags (T12 pattern, static idx) ----
      bf16x8 pf[4];
#pragma unroll
      for (int ks = 0; ks < 4; ++ks) {
        const int base = 16 * (ks >> 1) + 8 * (ks & 1);
        const unsigned g0 = pk2(p[base + 0], p[base + 1]);
        const unsigned g1 = pk2(p[base + 2], p[base + 3]);
        const unsigned g2 = pk2(p[base + 4], p[base + 5]);
        const unsigned g3 = pk2(p[base + 6], p[base + 7]);
        const unsigned e0 = __shfl_xor(hi ? g0 : g2, 32);
        const unsigned e1 = __shfl_xor(hi ? g1 : g3, 32);
        u32x4 w4;
        w4[0] = hi ? e0 : g0;
        w4[1] = hi ? e1 : g1;
        w4[2] = hi ? g2 : e0;
        w4[3] = hi ? g3 : e1;
        pf[ks] = __builtin_bit_cast(bf16x8, w4);
      }

      // ---- O^T += V^T . P^T ----
      __builtin_amdgcn_s_setprio(1);
#pragma unroll
      for (int ks = 0; ks < 4; ++ks) {
        const int cb = (32 * ks + 16 * hi) ^ (l7 << 4);
        const bf16x8 v0 = *(const bf16x8*)(Vs[cur] + q31 * 128 + cb);
        const bf16x8 v1 = *(const bf16x8*)(Vs[cur] + (32 + q31) * 128 + cb);
        O0 = MFMA32(v0, pf[ks], O0);
        O1 = MFMA32(v1, pf[ks], O1);
      }
      __builtin_amdgcn_s_setprio(0);
    }
    __syncthreads();
    cur ^= 1;
  }

  // ---- epilogue: normalize + store [B,T,C] ----
  const int b = bh >> 4, h = bh & 15;
  const float inv = 1.f / l;
  bf16* orow = attout + ((size_t)b * 2048 + qa) * 1024 + h * 64;
#pragma unroll
  for (int r = 0; r < 16; ++r) {
    const int dd = (r & 3) + 8 * (r >> 2) + 4 * hi;
    orow[dd]      = (bf16)(O0[r] * inv);
    orow[32 + dd] = (bf16)(O1[r] * inv);
  }
}

// ---------------------------------------------------------------------------
extern "C" void kernel_launch(void* const* d_in, const int* in_sizes, int n_in,
                              void* d_out, int out_size, void* d_ws, size_t ws_size,
                              hipStream_t stream) {
  const float* x   = (const float*)d_in[0];
  const float* xq  = (const float*)d_in[1];
  const float* Wq  = (const float*)d_in[2];
  const float* bq  = (const float*)d_in[3];
  const float* Wk  = (const float*)d_in[4];
  const float* bk  = (const float*)d_in[5];
  const float* Wv  = (const float*)d_in[6];
  const float* bv  = (const float*)d_in[7];
  const float* Wp  = (const float*)d_in[8];
  const float* bp  = (const float*)d_in[9];
  float* out = (float*)d_out;

  const size_t NTC = 4194304;  // B*T*C
  const size_t NW  = 1048576;  // C*C
  bf16* ws = (bf16*)d_ws;
  bf16* XQb = ws;
  bf16* Xb  = XQb + NTC;
  bf16* Wqb = Xb + NTC;
  bf16* Wkb = Wqb + NW;
  bf16* Wvb = Wkb + NW;
  bf16* Wpb = Wvb + NW;
  bf16* Qw  = Wpb + NW;              // [B*H, T, D]
  bf16* Kw  = Qw + NTC;
  bf16* Vtw = Kw + NTC;              // [B*H, D, T]
  bf16* Aw  = Vtw + NTC;             // [B, T, C]

  dim3 blk(256);
  cvt6<<<dim3(6144), blk, 0, stream>>>(xq, x, Wq, Wk, Wv, Wp,
                                       XQb, Xb, Wqb, Wkb, Wvb, Wpb);
  gemm_qkv<<<dim3(24, 32), blk, 0, stream>>>(XQb, Xb, Wqb, Wkb, Wvb,
                                             bq, bk, bv, Qw, Kw, Vtw);
  attn_fwd<<<dim3(512), blk, 0, stream>>>(Qw, Kw, Vtw, Aw);
  gemm_out<64><<<dim3(16, 32), blk, 0, stream>>>(Aw, Wpb, bp, out, 4096, 1024, 1024);
}